// Round 5
// baseline (161.527 us; speedup 1.0000x reference)
//
#include <hip/hip_runtime.h>
#include <cstdint>

#define HB 8
#define CM 128
#define NHEAD 8
#define NPT 8
#define DHD 16
#define HS 64
#define WS 64
#define LTOT 4096
#define NQA 192   // fused off(128) + attn(64)
#define QAP 196   // qaT LDS pitch (floats): 196%32=4 -> 4-way max on float4 reads; 32*196*4=25088 B
#define LFP 132   // gemm_val transpose pitch (floats): 132%32=4 spreads banks

typedef float floatx4 __attribute__((ext_vector_type(4)));
typedef short bf16x8 __attribute__((ext_vector_type(8)));

__device__ __forceinline__ unsigned short f2bf_rne(float x) {
  unsigned u = __float_as_uint(x);
  return (unsigned short)((u + 0x7FFFu + ((u >> 16) & 1)) >> 16);
}
__device__ __forceinline__ void split_bf(float x, unsigned short& h, unsigned short& l) {
  unsigned u = __float_as_uint(x);
  h = (unsigned short)(u >> 16);
  float r = x - __uint_as_float(u & 0xFFFF0000u);
  l = (unsigned short)(__float_as_uint(r) >> 16);
}
__device__ __forceinline__ float fast_tanh(float x) {
  float e = __expf(2.0f * x);
  return 1.0f - 2.0f / (e + 1.0f);
}
// unpack uint4 (8 bf16) -> 2x floatx4, fused multiply-accumulate by scalar wc
__device__ __forceinline__ void bf8_fma(floatx4& oa, floatx4& ob, const uint4 r, const float wc) {
  floatx4 va = {__uint_as_float(r.x << 16), __uint_as_float(r.x & 0xFFFF0000u),
                __uint_as_float(r.y << 16), __uint_as_float(r.y & 0xFFFF0000u)};
  floatx4 vb = {__uint_as_float(r.z << 16), __uint_as_float(r.z & 0xFFFF0000u),
                __uint_as_float(r.w << 16), __uint_as_float(r.w & 0xFFFF0000u)};
  oa += va * wc;
  ob += vb * wc;
}

// Weight prep -> bf16 hi/lo fragment layout: element (n,k) at (k>>3)*Nn*8 + n*8 + (k&7).
__global__ __launch_bounds__(256) void prep(const float* __restrict__ Wv,
                                            const float* __restrict__ Wo,
                                            const float* __restrict__ Wa,
                                            const float* __restrict__ Ww,
                                            const float* __restrict__ bo,
                                            const float* __restrict__ ba,
                                            unsigned short* __restrict__ wf_val,
                                            unsigned short* __restrict__ wf_qa,
                                            unsigned short* __restrict__ wf_out,
                                            float* __restrict__ bias_qa) {
  const int gid = blockIdx.x * 256 + threadIdx.x;  // 14336 = 32 k4 * 448 n
  const int k4 = gid / 448;
  const int ng = gid - k4 * 448;

  const float* src;
  unsigned short* dst;
  int Nsrc, Nn, nd, n;
  if (ng < 128) {        src = Wv; dst = wf_val; Nsrc = 128; Nn = 128; n = ng;        nd = n; }
  else if (ng < 256) {   src = Wo; dst = wf_qa;  Nsrc = 128; Nn = 192; n = ng - 128;  nd = n; }
  else if (ng < 320) {   src = Wa; dst = wf_qa;  Nsrc = 64;  Nn = 192; n = ng - 256;  nd = n + 128; }
  else {                 src = Ww; dst = wf_out; Nsrc = 128; Nn = 128; n = ng - 320;  nd = n; }

  ushort4 hi, lo;
  split_bf(src[(k4 * 4 + 0) * Nsrc + n], hi.x, lo.x);
  split_bf(src[(k4 * 4 + 1) * Nsrc + n], hi.y, lo.y);
  split_bf(src[(k4 * 4 + 2) * Nsrc + n], hi.z, lo.z);
  split_bf(src[(k4 * 4 + 3) * Nsrc + n], hi.w, lo.w);
  const int off = (k4 >> 1) * Nn * 8 + nd * 8 + (k4 & 1) * 4;
  *(ushort4*)(dst + off) = hi;
  *(ushort4*)(dst + Nn * 128 + off) = lo;

  if (gid < 128) bias_qa[gid] = bo[gid];
  else if (gid < 192) bias_qa[gid] = ba[gid - 128];
}

// K1: value projection. Tile 64 m x 128 n, 256 thr (4 waves, wave = 32m x 64n).
// 3-term bf16 split. Epilogue: LDS transpose -> COALESCED uint4 bf16 stores.
__global__ __launch_bounds__(256, 4) void gemm_val(const float* __restrict__ nbr,
                                                   const unsigned short* __restrict__ WF,
                                                   const float* __restrict__ bias,
                                                   unsigned short* __restrict__ value) {
  __shared__ __align__(16) char smem[33792];   // staging 32768; transpose 64*132*4=33792
  unsigned short* AB = (unsigned short*)smem;  // hi [64][128]; lo at +8192 us
  const int t = threadIdx.x;
  const int ml0 = blockIdx.x * 64;
  const int b = blockIdx.y;

  {
    const float* src = nbr + (size_t)b * CM * LTOT + ml0;
    const int x = t & 63, kq = t >> 6;
#pragma unroll
    for (int i = 0; i < 8; i++) {
      const int kb = kq * 4 + i * 16;
      ushort4 hi, lo;
      split_bf(src[(size_t)(kb + 0) * LTOT + x], hi.x, lo.x);
      split_bf(src[(size_t)(kb + 1) * LTOT + x], hi.y, lo.y);
      split_bf(src[(size_t)(kb + 2) * LTOT + x], hi.z, lo.z);
      split_bf(src[(size_t)(kb + 3) * LTOT + x], hi.w, lo.w);
      const int off = x * 128 + (((kb >> 3) ^ (x & 15)) << 3) + (kb & 7);
      *(ushort4*)(AB + off) = hi;
      *(ushort4*)(AB + 8192 + off) = lo;
    }
  }
  __syncthreads();

  const int w = t >> 6, lane = t & 63;
  const int wm = (w >> 1) * 32, wn = (w & 1) * 64;
  const int nl = lane & 15, q = lane >> 4;

  floatx4 acc[2][4];
#pragma unroll
  for (int mt = 0; mt < 2; mt++)
#pragma unroll
    for (int j = 0; j < 4; j++) acc[mt][j] = {0.0f, 0.0f, 0.0f, 0.0f};

#pragma unroll
  for (int K0 = 0; K0 < 4; K0++) {
    bf16x8 ah[2], al[2];
#pragma unroll
    for (int mt = 0; mt < 2; mt++) {
      const int m = wm + mt * 16 + nl;
      const int off = m * 128 + (((K0 * 4 + q) ^ (m & 15)) << 3);
      ah[mt] = *(bf16x8*)(AB + off);
      al[mt] = *(bf16x8*)(AB + 8192 + off);
    }
#pragma unroll
    for (int j = 0; j < 4; j++) {
      const size_t o = (size_t)(K0 * 4 + q) * CM * 8 + (wn + j * 16 + nl) * 8;
      const bf16x8 wh = *(const bf16x8*)(WF + o);
      const bf16x8 wl = *(const bf16x8*)(WF + (size_t)CM * 128 + o);
#pragma unroll
      for (int mt = 0; mt < 2; mt++) {
        acc[mt][j] = __builtin_amdgcn_mfma_f32_16x16x32_bf16(al[mt], wh, acc[mt][j], 0, 0, 0);
        acc[mt][j] = __builtin_amdgcn_mfma_f32_16x16x32_bf16(ah[mt], wl, acc[mt][j], 0, 0, 0);
        acc[mt][j] = __builtin_amdgcn_mfma_f32_16x16x32_bf16(ah[mt], wh, acc[mt][j], 0, 0, 0);
      }
    }
  }

  // ---- epilogue: acc -> LDS [64 l][132] fp32 -> packed bf16 uint4 coalesced stores ----
  __syncthreads();  // AB dead
  float* LF = (float*)smem;
#pragma unroll
  for (int j = 0; j < 4; j++) {
    const int gc = wn + j * 16 + nl;
    const float bv = bias[gc];
#pragma unroll
    for (int mt = 0; mt < 2; mt++)
#pragma unroll
      for (int r = 0; r < 4; r++)
        LF[(wm + mt * 16 + q * 4 + r) * LFP + gc] = acc[mt][j][r] + bv;
  }
  __syncthreads();
  // 1024 uint4 chunks: c = h(3b) | l(6b) | half(1b); wave writes contiguous 1 KB per h
#pragma unroll
  for (int i = 0; i < 4; i++) {
    const int c = t + i * 256;
    const int h = c >> 7, rem = c & 127, l = rem >> 1, half = rem & 1;
    const float* sp = LF + l * LFP + h * 16 + half * 8;
    uint4 st;
    st.x = ((unsigned)f2bf_rne(sp[1]) << 16) | f2bf_rne(sp[0]);
    st.y = ((unsigned)f2bf_rne(sp[3]) << 16) | f2bf_rne(sp[2]);
    st.z = ((unsigned)f2bf_rne(sp[5]) << 16) | f2bf_rne(sp[4]);
    st.w = ((unsigned)f2bf_rne(sp[7]) << 16) | f2bf_rne(sp[6]);
    *(uint4*)(value + ((size_t)(b * NHEAD + h) * LTOT + ml0 + l) * DHD + half * 8) = st;
  }
}

// K1b: corner-pair pack. P2[bh][y][x] = 64B = {v(y,x)ch0-7 | v(y,x+1)ch0-7 |
// v(y,x)ch8-15 | v(y,x+1)ch8-15} (x+1 edge-clamped). One bilinear point then
// reads exactly 2 aligned 64B lines (row y0 + row y0+1), fully consumed.
// Rationale: samp stuck at ~58us across occ 17-40% and 2x instr-count changes
// -> bound by scattered-L2-line traffic (~3 lines/point). P2 cuts to 2 contiguous.
// b = blockIdx&7 -> same XCD as samp's consumers; P2 = 2.1 MB/XCD, L2-resident.
__global__ __launch_bounds__(256) void qpack(const unsigned short* __restrict__ value,
                                             unsigned short* __restrict__ p2) {
  const int b = blockIdx.x & 7;
  const int chunk = blockIdx.x >> 3;  // 0..127
  const int h = chunk >> 4;           // 0..7
  const int y = (chunk & 15) * 4 + (threadIdx.x >> 6);
  const int x = threadIdx.x & 63;
  const int bh = b * NHEAD + h;
  const unsigned short* vb = value + (size_t)bh * LTOT * DHD;
  const int xp = min(x + 1, WS - 1);
  const uint4* s0 = (const uint4*)(vb + (y * WS + x) * DHD);
  const uint4* s1 = (const uint4*)(vb + (y * WS + xp) * DHD);
  const uint4 c0h0 = s0[0], c0h1 = s0[1];
  const uint4 c1h0 = s1[0], c1h1 = s1[1];
  uint4* d = (uint4*)(p2 + ((size_t)bh * LTOT + y * WS + x) * 32);
  d[0] = c0h0;
  d[1] = c1h0;
  d[2] = c0h1;
  d[3] = c1h1;
}

// K2: per 32-l tile: stage ext -> qa GEMM -> sampling params in REGISTERS ->
// gather from P2 in TWO CHANNEL-HALVES -> out GEMM.
// Gather weights in absolute-pixel hat form: w(s) = a*max(0,1-|px-X|)*max(0,1-|py-Y|),
// with x+1/y+1 slots zeroed at the image edge -- identical to reference fx/fy form.
// Spill guard: samp hbm_bytes must stay ~3.0e7.
__global__ __launch_bounds__(256, 2) void samp(const float* __restrict__ ext,
                                               const unsigned short* __restrict__ p2,
                                               const unsigned short* __restrict__ wf_qa,
                                               const unsigned short* __restrict__ wf_out,
                                               const float* __restrict__ bias_qa,
                                               const float* __restrict__ b_out,
                                               float* __restrict__ out) {
  __shared__ __align__(16) char smem[25088];
  unsigned short* AB = (unsigned short*)smem;  // [32][128] hi; lo at +4096 us (16384 B)
  float* qaT = (float*)smem;                   // [32][QAP] = 25088 B (after AB dead)
  unsigned short* FR = (unsigned short*)smem;  // [32][128] bf16 = 8192 B (after qaT dead)

  const int t = threadIdx.x;
  const int b = blockIdx.x & 7;                // XCD affinity
  const int ml0 = (blockIdx.x >> 3) * 32;
  const int w = t >> 6, lane = t & 63;
  const int nl = lane & 15, q = lane >> 4;

  // ---- stage ext 32-l tile (fp32 -> bf16 hi/lo, swizzled) ----
  {
    const float* src = ext + (size_t)b * CM * LTOT + ml0;
    const int x = t & 31, kq = t >> 5;  // kq 0..7
#pragma unroll
    for (int i = 0; i < 4; i++) {
      const int kb = i * 32 + kq * 4;
      ushort4 hi, lo;
      split_bf(src[(size_t)(kb + 0) * LTOT + x], hi.x, lo.x);
      split_bf(src[(size_t)(kb + 1) * LTOT + x], hi.y, lo.y);
      split_bf(src[(size_t)(kb + 2) * LTOT + x], hi.z, lo.z);
      split_bf(src[(size_t)(kb + 3) * LTOT + x], hi.w, lo.w);
      const int off = x * 128 + (((kb >> 3) ^ (x & 15)) << 3) + (kb & 7);
      *(ushort4*)(AB + off) = hi;
      *(ushort4*)(AB + 4096 + off) = lo;
    }
  }
  __syncthreads();

  // ---- qa GEMM: 32m x 192n, 4 waves, wave = 16m x 96n; result -> qaT (LDS, overlaps AB) ----
  {
    const int wm = (w & 1) * 16;
    const int wn = (w >> 1) * 96;
    floatx4 acc[6];
#pragma unroll
    for (int j = 0; j < 6; j++) acc[j] = {0.0f, 0.0f, 0.0f, 0.0f};
#pragma unroll
    for (int K0 = 0; K0 < 4; K0++) {
      const int m = wm + nl;
      const int off = m * 128 + (((K0 * 4 + q) ^ (m & 15)) << 3);
      const bf16x8 ah = *(bf16x8*)(AB + off);
      const bf16x8 al = *(bf16x8*)(AB + 4096 + off);
#pragma unroll
      for (int j = 0; j < 6; j++) {
        const size_t o = (size_t)(K0 * 4 + q) * NQA * 8 + (wn + j * 16 + nl) * 8;
        const bf16x8 wh = *(const bf16x8*)(wf_qa + o);
        const bf16x8 wl = *(const bf16x8*)(wf_qa + (size_t)NQA * 128 + o);
        acc[j] = __builtin_amdgcn_mfma_f32_16x16x32_bf16(al, wh, acc[j], 0, 0, 0);
        acc[j] = __builtin_amdgcn_mfma_f32_16x16x32_bf16(ah, wl, acc[j], 0, 0, 0);
        acc[j] = __builtin_amdgcn_mfma_f32_16x16x32_bf16(ah, wh, acc[j], 0, 0, 0);
      }
    }
    __syncthreads();  // all AB reads done -> qaT may overwrite
#pragma unroll
    for (int j = 0; j < 6; j++) {
      const int n = wn + j * 16 + nl;
      const float bv = bias_qa[n];
#pragma unroll
      for (int r = 0; r < 4; r++)
        qaT[(wm + q * 4 + r) * QAP + n] = acc[j][r] + bv;
    }
  }
  __syncthreads();

  // ---- sampling params -> REGISTERS; thread t = (ll = t>>3, h = t&7), same as gather ----
  float px[8], py[8], aw[8];
  const int ll = t >> 3, h = t & 7;
  {
    const float* qrow = qaT + ll * QAP;
    float4 of[4];
#pragma unroll
    for (int j = 0; j < 4; j++) of[j] = *(const float4*)(qrow + h * 16 + j * 4);
    const float4 lga = *(const float4*)(qrow + 128 + h * 8);
    const float4 lgb = *(const float4*)(qrow + 128 + h * 8 + 4);
    const float lg[8] = {lga.x, lga.y, lga.z, lga.w, lgb.x, lgb.y, lgb.z, lgb.w};
    float m = lg[0];
#pragma unroll
    for (int p = 1; p < 8; p++) m = fmaxf(m, lg[p]);
    float e[8], s = 0.0f;
#pragma unroll
    for (int p = 0; p < 8; p++) { e[p] = __expf(lg[p] - m); s += e[p]; }
    const float inv = 1.0f / s;
    const int l = ml0 + ll;
    const float xf = (float)(l & (WS - 1));
    const float yf = (float)(l >> 6);
#pragma unroll
    for (int p = 0; p < 8; p++) {
      const float ox = (p & 1) ? of[p >> 1].z : of[p >> 1].x;
      const float oy = (p & 1) ? of[p >> 1].w : of[p >> 1].y;
      px[p] = xf + 10.0f * fast_tanh(ox);
      py[p] = yf + 10.0f * fast_tanh(oy);
      aw[p] = e[p] * inv;
    }
  }
  __syncthreads();  // qaT dead -> FR may be written

  // ---- gather from P2: two channel-halves; per point = 2 contiguous 64B lines ----
  {
    const size_t pb = (size_t)(b * NHEAD + h) * LTOT * 32;  // us offset of P2 plane
    const int llm = ll & 15;
#pragma unroll
    for (int hf = 0; hf < 2; hf++) {
      floatx4 oa = {0.f, 0.f, 0.f, 0.f}, ob = oa;
#pragma unroll
      for (int p = 0; p < 8; p++) {
        const float x0f = floorf(px[p]), y0f = floorf(py[p]);
        const int qx = min(max((int)x0f, 0), WS - 1);
        const int qy = min(max((int)y0f, 0), HS - 1);
        const float tx = px[p] - (float)qx;
        const float ty = py[p] - (float)qy;
        const float hx0 = fmaxf(0.0f, 1.0f - fabsf(tx));
        float hx1 = fmaxf(0.0f, 1.0f - fabsf(tx - 1.0f));
        const float hy0 = fmaxf(0.0f, 1.0f - fabsf(ty));
        float hy1 = fmaxf(0.0f, 1.0f - fabsf(ty - 1.0f));
        if (qx + 1 >= WS) hx1 = 0.0f;
        if (qy + 1 >= HS) hy1 = 0.0f;
        const float a = aw[p];
        const float ay0 = a * hy0, ay1 = a * hy1;
        const unsigned r0 = (unsigned)(qy * WS + qx) * 32 + hf * 16;
        const unsigned r1 = (unsigned)(min(qy + 1, HS - 1) * WS + qx) * 32 + hf * 16;
        const uint4* a0 = (const uint4*)(p2 + pb + r0);
        const uint4* a1 = (const uint4*)(p2 + pb + r1);
        const uint4 v00 = a0[0], v01 = a0[1];
        const uint4 v10 = a1[0], v11 = a1[1];
        bf8_fma(oa, ob, v00, ay0 * hx0);
        bf8_fma(oa, ob, v01, ay0 * hx1);
        bf8_fma(oa, ob, v10, ay1 * hx0);
        bf8_fma(oa, ob, v11, ay1 * hx1);
      }
      // write FR: swizzled uint4; group g = h*2+hf holds channels g*8..g*8+7
      const int off = ll * 128 + (((h * 2 + hf) ^ llm) << 3);
      uint4 st;
      st.x = ((unsigned)f2bf_rne(oa[1]) << 16) | f2bf_rne(oa[0]);
      st.y = ((unsigned)f2bf_rne(oa[3]) << 16) | f2bf_rne(oa[2]);
      st.z = ((unsigned)f2bf_rne(ob[1]) << 16) | f2bf_rne(ob[0]);
      st.w = ((unsigned)f2bf_rne(ob[3]) << 16) | f2bf_rne(ob[2]);
      *(uint4*)(FR + off) = st;
    }
  }
  __syncthreads();

  // ---- out GEMM: 32m x 128n, 4 waves, wave = 16m x 64n; direct float4 stores ----
  {
    const int wm = (w & 1) * 16;
    const int wn = (w >> 1) * 64;
    floatx4 acc[4];
#pragma unroll
    for (int j = 0; j < 4; j++) acc[j] = {0.0f, 0.0f, 0.0f, 0.0f};
#pragma unroll
    for (int K0 = 0; K0 < 4; K0++) {
      const int m = wm + nl;
      const int off = m * 128 + (((K0 * 4 + q) ^ (m & 15)) << 3);
      const bf16x8 ah = *(bf16x8*)(FR + off);
#pragma unroll
      for (int j = 0; j < 4; j++) {
        const int n = wn + j * 16 + nl;
        const size_t o = (size_t)(K0 * 4 + q) * CM * 8 + n * 8;
        const bf16x8 wh = *(const bf16x8*)(wf_out + o);
        const bf16x8 wl = *(const bf16x8*)(wf_out + (size_t)CM * 128 + o);
        acc[j] = __builtin_amdgcn_mfma_f32_16x16x32_bf16(ah, wl, acc[j], 0, 0, 0);
        acc[j] = __builtin_amdgcn_mfma_f32_16x16x32_bf16(ah, wh, acc[j], 0, 0, 0);
      }
    }
    // C/D: col=nl -> n, rows q*4+r -> m (contiguous in bchw) => float4 store
#pragma unroll
    for (int j = 0; j < 4; j++) {
      const int gc = wn + j * 16 + nl;
      const float bv = b_out[gc];
      float4 st = {acc[j][0] + bv, acc[j][1] + bv, acc[j][2] + bv, acc[j][3] + bv};
      *(float4*)(out + ((size_t)b * CM + gc) * LTOT + ml0 + wm + q * 4) = st;
    }
  }
}

extern "C" void kernel_launch(void* const* d_in, const int* in_sizes, int n_in,
                              void* d_out, int out_size, void* d_ws, size_t ws_size,
                              hipStream_t stream) {
  const float* nbr    = (const float*)d_in[0];
  const float* ext    = (const float*)d_in[1];
  const float* W_val  = (const float*)d_in[2];
  const float* b_val  = (const float*)d_in[3];
  const float* W_off  = (const float*)d_in[4];
  const float* b_off  = (const float*)d_in[5];
  const float* W_attn = (const float*)d_in[6];
  const float* b_attn = (const float*)d_in[7];
  const float* W_out  = (const float*)d_in[8];
  const float* b_out  = (const float*)d_in[9];
  float* out = (float*)d_out;

  unsigned short* value = (unsigned short*)d_ws;                      // 8.39 MB bf16 [b][h][l][16]
  unsigned short* p2    = value + (size_t)HB * NHEAD * LTOT * DHD;    // 16.78 MB corner-pair packed
  unsigned short* wf_val = p2 + (size_t)HB * NHEAD * LTOT * 32;       // 64 KB
  unsigned short* wf_qa  = wf_val + 128 * 128 * 2;                    // 96 KB
  unsigned short* wf_out = wf_qa + 192 * 128 * 2;                     // 64 KB
  float* bias_qa = (float*)(wf_out + 128 * 128 * 2);                  // 768 B

  prep<<<56, 256, 0, stream>>>(W_val, W_off, W_attn, W_out, b_off, b_attn,
                               wf_val, wf_qa, wf_out, bias_qa);
  gemm_val<<<dim3(64, HB), 256, 0, stream>>>(nbr, wf_val, b_val, value);
  qpack<<<1024, 256, 0, stream>>>(value, p2);
  samp<<<dim3(128 * HB), 256, 0, stream>>>(ext, p2, wf_qa, wf_out, bias_qa, b_out, out);
}

// Round 6
// 136.601 us; speedup vs baseline: 1.1825x; 1.1825x over previous
//
#include <hip/hip_runtime.h>
#include <cstdint>

#define HB 8
#define CM 128
#define NHEAD 8
#define NPT 8
#define DHD 16
#define HS 64
#define WS 64
#define LTOT 4096
#define NQA 192   // fused off(128) + attn(64)
#define QAP 196   // qaT LDS pitch (floats): 196%32=4; 32*196*4=25088 B
#define LFP 132   // gemm_val transpose pitch (floats): 132%32=4 spreads banks
#define WPP 33    // WXY/WA pitch (entries) per (h,p) row: 33 breaks pow2 banks

typedef float floatx4 __attribute__((ext_vector_type(4)));
typedef short bf16x8 __attribute__((ext_vector_type(8)));

__device__ __forceinline__ unsigned short f2bf_rne(float x) {
  unsigned u = __float_as_uint(x);
  return (unsigned short)((u + 0x7FFFu + ((u >> 16) & 1)) >> 16);
}
__device__ __forceinline__ void split_bf(float x, unsigned short& h, unsigned short& l) {
  unsigned u = __float_as_uint(x);
  h = (unsigned short)(u >> 16);
  float r = x - __uint_as_float(u & 0xFFFF0000u);
  l = (unsigned short)(__float_as_uint(r) >> 16);
}
__device__ __forceinline__ float fast_tanh(float x) {
  float e = __expf(2.0f * x);
  return 1.0f - 2.0f / (e + 1.0f);
}
// unpack uint4 (8 bf16) -> 2x floatx4, fused multiply-accumulate by scalar wc
__device__ __forceinline__ void bf8_fma(floatx4& oa, floatx4& ob, const uint4 r, const float wc) {
  floatx4 va = {__uint_as_float(r.x << 16), __uint_as_float(r.x & 0xFFFF0000u),
                __uint_as_float(r.y << 16), __uint_as_float(r.y & 0xFFFF0000u)};
  floatx4 vb = {__uint_as_float(r.z << 16), __uint_as_float(r.z & 0xFFFF0000u),
                __uint_as_float(r.w << 16), __uint_as_float(r.w & 0xFFFF0000u)};
  oa += va * wc;
  ob += vb * wc;
}

// Weight prep -> bf16 hi/lo fragment layout: element (n,k) at (k>>3)*Nn*8 + n*8 + (k&7).
__global__ __launch_bounds__(256) void prep(const float* __restrict__ Wv,
                                            const float* __restrict__ Wo,
                                            const float* __restrict__ Wa,
                                            const float* __restrict__ Ww,
                                            const float* __restrict__ bo,
                                            const float* __restrict__ ba,
                                            unsigned short* __restrict__ wf_val,
                                            unsigned short* __restrict__ wf_qa,
                                            unsigned short* __restrict__ wf_out,
                                            float* __restrict__ bias_qa) {
  const int gid = blockIdx.x * 256 + threadIdx.x;  // 14336 = 32 k4 * 448 n
  const int k4 = gid / 448;
  const int ng = gid - k4 * 448;

  const float* src;
  unsigned short* dst;
  int Nsrc, Nn, nd, n;
  if (ng < 128) {        src = Wv; dst = wf_val; Nsrc = 128; Nn = 128; n = ng;        nd = n; }
  else if (ng < 256) {   src = Wo; dst = wf_qa;  Nsrc = 128; Nn = 192; n = ng - 128;  nd = n; }
  else if (ng < 320) {   src = Wa; dst = wf_qa;  Nsrc = 64;  Nn = 192; n = ng - 256;  nd = n + 128; }
  else {                 src = Ww; dst = wf_out; Nsrc = 128; Nn = 128; n = ng - 320;  nd = n; }

  ushort4 hi, lo;
  split_bf(src[(k4 * 4 + 0) * Nsrc + n], hi.x, lo.x);
  split_bf(src[(k4 * 4 + 1) * Nsrc + n], hi.y, lo.y);
  split_bf(src[(k4 * 4 + 2) * Nsrc + n], hi.z, lo.z);
  split_bf(src[(k4 * 4 + 3) * Nsrc + n], hi.w, lo.w);
  const int off = (k4 >> 1) * Nn * 8 + nd * 8 + (k4 & 1) * 4;
  *(ushort4*)(dst + off) = hi;
  *(ushort4*)(dst + Nn * 128 + off) = lo;

  if (gid < 128) bias_qa[gid] = bo[gid];
  else if (gid < 192) bias_qa[gid] = ba[gid - 128];
}

// K1: value projection. Tile 64 m x 128 n, 256 thr (4 waves, wave = 32m x 64n).
// 3-term bf16 split. Epilogue: LDS transpose -> COALESCED uint4 bf16 stores.
__global__ __launch_bounds__(256, 4) void gemm_val(const float* __restrict__ nbr,
                                                   const unsigned short* __restrict__ WF,
                                                   const float* __restrict__ bias,
                                                   unsigned short* __restrict__ value) {
  __shared__ __align__(16) char smem[33792];   // staging 32768; transpose 64*132*4=33792
  unsigned short* AB = (unsigned short*)smem;  // hi [64][128]; lo at +8192 us
  const int t = threadIdx.x;
  const int ml0 = blockIdx.x * 64;
  const int b = blockIdx.y;

  {
    const float* src = nbr + (size_t)b * CM * LTOT + ml0;
    const int x = t & 63, kq = t >> 6;
#pragma unroll
    for (int i = 0; i < 8; i++) {
      const int kb = kq * 4 + i * 16;
      ushort4 hi, lo;
      split_bf(src[(size_t)(kb + 0) * LTOT + x], hi.x, lo.x);
      split_bf(src[(size_t)(kb + 1) * LTOT + x], hi.y, lo.y);
      split_bf(src[(size_t)(kb + 2) * LTOT + x], hi.z, lo.z);
      split_bf(src[(size_t)(kb + 3) * LTOT + x], hi.w, lo.w);
      const int off = x * 128 + (((kb >> 3) ^ (x & 15)) << 3) + (kb & 7);
      *(ushort4*)(AB + off) = hi;
      *(ushort4*)(AB + 8192 + off) = lo;
    }
  }
  __syncthreads();

  const int w = t >> 6, lane = t & 63;
  const int wm = (w >> 1) * 32, wn = (w & 1) * 64;
  const int nl = lane & 15, q = lane >> 4;

  floatx4 acc[2][4];
#pragma unroll
  for (int mt = 0; mt < 2; mt++)
#pragma unroll
    for (int j = 0; j < 4; j++) acc[mt][j] = {0.0f, 0.0f, 0.0f, 0.0f};

#pragma unroll
  for (int K0 = 0; K0 < 4; K0++) {
    bf16x8 ah[2], al[2];
#pragma unroll
    for (int mt = 0; mt < 2; mt++) {
      const int m = wm + mt * 16 + nl;
      const int off = m * 128 + (((K0 * 4 + q) ^ (m & 15)) << 3);
      ah[mt] = *(bf16x8*)(AB + off);
      al[mt] = *(bf16x8*)(AB + 8192 + off);
    }
#pragma unroll
    for (int j = 0; j < 4; j++) {
      const size_t o = (size_t)(K0 * 4 + q) * CM * 8 + (wn + j * 16 + nl) * 8;
      const bf16x8 wh = *(const bf16x8*)(WF + o);
      const bf16x8 wl = *(const bf16x8*)(WF + (size_t)CM * 128 + o);
#pragma unroll
      for (int mt = 0; mt < 2; mt++) {
        acc[mt][j] = __builtin_amdgcn_mfma_f32_16x16x32_bf16(al[mt], wh, acc[mt][j], 0, 0, 0);
        acc[mt][j] = __builtin_amdgcn_mfma_f32_16x16x32_bf16(ah[mt], wl, acc[mt][j], 0, 0, 0);
        acc[mt][j] = __builtin_amdgcn_mfma_f32_16x16x32_bf16(ah[mt], wh, acc[mt][j], 0, 0, 0);
      }
    }
  }

  // ---- epilogue: acc -> LDS [64 l][132] fp32 -> packed bf16 uint4 coalesced stores ----
  __syncthreads();  // AB dead
  float* LF = (float*)smem;
#pragma unroll
  for (int j = 0; j < 4; j++) {
    const int gc = wn + j * 16 + nl;
    const float bv = bias[gc];
#pragma unroll
    for (int mt = 0; mt < 2; mt++)
#pragma unroll
      for (int r = 0; r < 4; r++)
        LF[(wm + mt * 16 + q * 4 + r) * LFP + gc] = acc[mt][j][r] + bv;
  }
  __syncthreads();
  // 1024 uint4 chunks: c = h(3b) | l(6b) | half(1b); wave writes contiguous 1 KB per h
#pragma unroll
  for (int i = 0; i < 4; i++) {
    const int c = t + i * 256;
    const int h = c >> 7, rem = c & 127, l = rem >> 1, half = rem & 1;
    const float* sp = LF + l * LFP + h * 16 + half * 8;
    uint4 st;
    st.x = ((unsigned)f2bf_rne(sp[1]) << 16) | f2bf_rne(sp[0]);
    st.y = ((unsigned)f2bf_rne(sp[3]) << 16) | f2bf_rne(sp[2]);
    st.z = ((unsigned)f2bf_rne(sp[5]) << 16) | f2bf_rne(sp[4]);
    st.w = ((unsigned)f2bf_rne(sp[7]) << 16) | f2bf_rne(sp[6]);
    *(uint4*)(value + ((size_t)(b * NHEAD + h) * LTOT + ml0 + l) * DHD + half * 8) = st;
  }
}

// K2: stage ext -> qa GEMM -> params -> WXY/WA (LDS) -> H-SEQUENCED gather -> out GEMM.
// R5 falsified the line-layout theory (P2 pack: no gain). New theory: gather is
// L1-window-thrash-bound. Offsets are 10*tanh(~0.2) ~ +-3 px -> per-(block,h) value
// window ~12 KB (fits 32KB L1), but the old (ll,h)-lane layout touches 8 head planes
// per instruction -> 8-way L1 thrash, zero reuse. Fix: wave w owns head h=w then w+4;
// lanes = (ll, ch-half); per instruction all lanes read same (h,p,corner) at ~32
// consecutive pixels -> contiguous spans, L1-resident across the 8 points x 4 corners.
// Params cross thread-mappings via WXY/WA LDS (24.8 KB over dead qaT). LDS 33792 ->
// 4 blocks/CU. Spill guard: hbm_bytes must stay ~3.0e7.
__global__ __launch_bounds__(256, 2) void samp(const float* __restrict__ ext,
                                               const unsigned short* __restrict__ value,
                                               const unsigned short* __restrict__ wf_qa,
                                               const unsigned short* __restrict__ wf_out,
                                               const float* __restrict__ bias_qa,
                                               const float* __restrict__ b_out,
                                               float* __restrict__ out) {
  __shared__ __align__(16) char smem[33792];
  unsigned short* AB = (unsigned short*)smem;   // [0,16384): staging hi/lo
  float* qaT = (float*)smem;                    // [0,25088)
  float2* WXY = (float2*)smem;                  // [8h*8p][WPP] float2 = 16896 B at 0
  float* WA = (float*)(smem + 16896);           // [8h*8p][WPP] float  =  8448 B
  unsigned short* FR = (unsigned short*)(smem + 25344);  // [32][128] bf16 = 8192 B

  const int t = threadIdx.x;
  const int b = blockIdx.x & 7;                // XCD affinity
  const int ml0 = (blockIdx.x >> 3) * 32;
  const int w = t >> 6, lane = t & 63;
  const int nl = lane & 15, q = lane >> 4;

  // ---- stage ext 32-l tile (fp32 -> bf16 hi/lo, swizzled) ----
  {
    const float* src = ext + (size_t)b * CM * LTOT + ml0;
    const int x = t & 31, kq = t >> 5;  // kq 0..7
#pragma unroll
    for (int i = 0; i < 4; i++) {
      const int kb = i * 32 + kq * 4;
      ushort4 hi, lo;
      split_bf(src[(size_t)(kb + 0) * LTOT + x], hi.x, lo.x);
      split_bf(src[(size_t)(kb + 1) * LTOT + x], hi.y, lo.y);
      split_bf(src[(size_t)(kb + 2) * LTOT + x], hi.z, lo.z);
      split_bf(src[(size_t)(kb + 3) * LTOT + x], hi.w, lo.w);
      const int off = x * 128 + (((kb >> 3) ^ (x & 15)) << 3) + (kb & 7);
      *(ushort4*)(AB + off) = hi;
      *(ushort4*)(AB + 4096 + off) = lo;
    }
  }
  __syncthreads();

  // ---- qa GEMM: 32m x 192n, 4 waves, wave = 16m x 96n; result -> qaT (LDS) ----
  {
    const int wm = (w & 1) * 16;
    const int wn = (w >> 1) * 96;
    floatx4 acc[6];
#pragma unroll
    for (int j = 0; j < 6; j++) acc[j] = {0.0f, 0.0f, 0.0f, 0.0f};
#pragma unroll
    for (int K0 = 0; K0 < 4; K0++) {
      const int m = wm + nl;
      const int off = m * 128 + (((K0 * 4 + q) ^ (m & 15)) << 3);
      const bf16x8 ah = *(bf16x8*)(AB + off);
      const bf16x8 al = *(bf16x8*)(AB + 4096 + off);
#pragma unroll
      for (int j = 0; j < 6; j++) {
        const size_t o = (size_t)(K0 * 4 + q) * NQA * 8 + (wn + j * 16 + nl) * 8;
        const bf16x8 wh = *(const bf16x8*)(wf_qa + o);
        const bf16x8 wl = *(const bf16x8*)(wf_qa + (size_t)NQA * 128 + o);
        acc[j] = __builtin_amdgcn_mfma_f32_16x16x32_bf16(al, wh, acc[j], 0, 0, 0);
        acc[j] = __builtin_amdgcn_mfma_f32_16x16x32_bf16(ah, wl, acc[j], 0, 0, 0);
        acc[j] = __builtin_amdgcn_mfma_f32_16x16x32_bf16(ah, wh, acc[j], 0, 0, 0);
      }
    }
    __syncthreads();  // all AB reads done -> qaT may overwrite
#pragma unroll
    for (int j = 0; j < 6; j++) {
      const int n = wn + j * 16 + nl;
      const float bv = bias_qa[n];
#pragma unroll
      for (int r = 0; r < 4; r++)
        qaT[(wm + q * 4 + r) * QAP + n] = acc[j][r] + bv;
    }
  }
  __syncthreads();

  // ---- sampling params: thread (ll = t>>3, h = t&7) -> WXY/WA LDS ----
  {
    const int ll = t >> 3, h = t & 7;
    const float* qrow = qaT + ll * QAP;
    float4 of[4];
#pragma unroll
    for (int j = 0; j < 4; j++) of[j] = *(const float4*)(qrow + h * 16 + j * 4);
    const float4 lga = *(const float4*)(qrow + 128 + h * 8);
    const float4 lgb = *(const float4*)(qrow + 128 + h * 8 + 4);
    __syncthreads();  // qaT fully read -> WXY/WA may overwrite
    const float lg[8] = {lga.x, lga.y, lga.z, lga.w, lgb.x, lgb.y, lgb.z, lgb.w};
    float m = lg[0];
#pragma unroll
    for (int p = 1; p < 8; p++) m = fmaxf(m, lg[p]);
    float e[8], s = 0.0f;
#pragma unroll
    for (int p = 0; p < 8; p++) { e[p] = __expf(lg[p] - m); s += e[p]; }
    const float inv = 1.0f / s;
    const int l = ml0 + ll;
    const float xf = (float)(l & (WS - 1));
    const float yf = (float)(l >> 6);
#pragma unroll
    for (int p = 0; p < 8; p++) {
      const float ox = (p & 1) ? of[p >> 1].z : of[p >> 1].x;
      const float oy = (p & 1) ? of[p >> 1].w : of[p >> 1].y;
      WXY[(h * 8 + p) * WPP + ll] = {xf + 10.0f * fast_tanh(ox), yf + 10.0f * fast_tanh(oy)};
      WA[(h * 8 + p) * WPP + ll] = e[p] * inv;
    }
  }
  __syncthreads();

  // ---- gather: wave w handles h = w, w+4; lane = (llq = lane>>1, half = lane&1) ----
  {
    const int llq = lane >> 1, half = lane & 1;
    const int llm = llq & 15;
#pragma unroll
    for (int hi2 = 0; hi2 < 2; hi2++) {
      const int hh = w + hi2 * 4;  // wave-uniform head
      const unsigned short* vb = value + (size_t)(b * NHEAD + hh) * LTOT * DHD + half * 8;
      floatx4 oa = {0.f, 0.f, 0.f, 0.f}, ob = oa;
#pragma unroll
      for (int p = 0; p < 8; p++) {
        const float2 pxy = WXY[(hh * 8 + p) * WPP + llq];
        const float a = WA[(hh * 8 + p) * WPP + llq];
        const float x0f = floorf(pxy.x), y0f = floorf(pxy.y);
        const float fx = pxy.x - x0f, fy = pxy.y - y0f;
        const int ix = (int)x0f, iy = (int)y0f;
        float wc[4];
        unsigned adr[4];
#pragma unroll
        for (int c = 0; c < 4; c++) {
          const int cdx = c & 1, cdy = c >> 1;
          const int jx = ix + cdx, jy = iy + cdy;
          const float wx = cdx ? fx : 1.0f - fx;
          const float wy = cdy ? fy : 1.0f - fy;
          const bool valid = ((unsigned)jx < WS) & ((unsigned)jy < HS);
          wc[c] = valid ? a * wx * wy : 0.0f;
          const int cx = min(max(jx, 0), WS - 1);
          const int cy = min(max(jy, 0), HS - 1);
          adr[c] = (unsigned)((cy << 6) + cx) * DHD;
        }
        uint4 r[4];
#pragma unroll
        for (int c = 0; c < 4; c++) r[c] = *(const uint4*)(vb + adr[c]);
#pragma unroll
        for (int c = 0; c < 4; c++) bf8_fma(oa, ob, r[c], wc[c]);
      }
      // FR: group g = hh*2+half holds channels g*8..g*8+7, swizzled by llm
      const int off = llq * 128 + (((hh * 2 + half) ^ llm) << 3);
      uint4 st;
      st.x = ((unsigned)f2bf_rne(oa[1]) << 16) | f2bf_rne(oa[0]);
      st.y = ((unsigned)f2bf_rne(oa[3]) << 16) | f2bf_rne(oa[2]);
      st.z = ((unsigned)f2bf_rne(ob[1]) << 16) | f2bf_rne(ob[0]);
      st.w = ((unsigned)f2bf_rne(ob[3]) << 16) | f2bf_rne(ob[2]);
      *(uint4*)(FR + off) = st;
    }
  }
  __syncthreads();

  // ---- out GEMM: 32m x 128n, 4 waves, wave = 16m x 64n; direct float4 stores ----
  {
    const int wm = (w & 1) * 16;
    const int wn = (w >> 1) * 64;
    floatx4 acc[4];
#pragma unroll
    for (int j = 0; j < 4; j++) acc[j] = {0.0f, 0.0f, 0.0f, 0.0f};
#pragma unroll
    for (int K0 = 0; K0 < 4; K0++) {
      const int m = wm + nl;
      const int off = m * 128 + (((K0 * 4 + q) ^ (m & 15)) << 3);
      const bf16x8 ah = *(bf16x8*)(FR + off);
#pragma unroll
      for (int j = 0; j < 4; j++) {
        const int n = wn + j * 16 + nl;
        const size_t o = (size_t)(K0 * 4 + q) * CM * 8 + n * 8;
        const bf16x8 wh = *(const bf16x8*)(wf_out + o);
        const bf16x8 wl = *(const bf16x8*)(wf_out + (size_t)CM * 128 + o);
        acc[j] = __builtin_amdgcn_mfma_f32_16x16x32_bf16(ah, wl, acc[j], 0, 0, 0);
        acc[j] = __builtin_amdgcn_mfma_f32_16x16x32_bf16(ah, wh, acc[j], 0, 0, 0);
      }
    }
    // C/D: col=nl -> n, rows q*4+r -> m (contiguous in bchw) => float4 store
#pragma unroll
    for (int j = 0; j < 4; j++) {
      const int gc = wn + j * 16 + nl;
      const float bv = b_out[gc];
      float4 st = {acc[j][0] + bv, acc[j][1] + bv, acc[j][2] + bv, acc[j][3] + bv};
      *(float4*)(out + ((size_t)b * CM + gc) * LTOT + ml0 + wm + q * 4) = st;
    }
  }
}

extern "C" void kernel_launch(void* const* d_in, const int* in_sizes, int n_in,
                              void* d_out, int out_size, void* d_ws, size_t ws_size,
                              hipStream_t stream) {
  const float* nbr    = (const float*)d_in[0];
  const float* ext    = (const float*)d_in[1];
  const float* W_val  = (const float*)d_in[2];
  const float* b_val  = (const float*)d_in[3];
  const float* W_off  = (const float*)d_in[4];
  const float* b_off  = (const float*)d_in[5];
  const float* W_attn = (const float*)d_in[6];
  const float* b_attn = (const float*)d_in[7];
  const float* W_out  = (const float*)d_in[8];
  const float* b_out  = (const float*)d_in[9];
  float* out = (float*)d_out;

  unsigned short* value = (unsigned short*)d_ws;             // 8.39 MB bf16 [b][h][l][16]
  unsigned short* wf_val = value + (size_t)HB * NHEAD * LTOT * DHD;  // 64 KB
  unsigned short* wf_qa  = wf_val + 128 * 128 * 2;           // 96 KB
  unsigned short* wf_out = wf_qa + 192 * 128 * 2;            // 64 KB
  float* bias_qa = (float*)(wf_out + 128 * 128 * 2);         // 768 B

  prep<<<56, 256, 0, stream>>>(W_val, W_off, W_attn, W_out, b_off, b_attn,
                               wf_val, wf_qa, wf_out, bias_qa);
  gemm_val<<<dim3(64, HB), 256, 0, stream>>>(nbr, wf_val, b_val, value);
  samp<<<dim3(128 * HB), 256, 0, stream>>>(ext, value, wf_qa, wf_out, bias_qa, b_out, out);
}

// Round 7
// 132.075 us; speedup vs baseline: 1.2230x; 1.0343x over previous
//
#include <hip/hip_runtime.h>
#include <cstdint>

#define HB 8
#define CM 128
#define NHEAD 8
#define NPT 8
#define DHD 16
#define HS 64
#define WS 64
#define LTOT 4096
#define NQA 192   // fused off(128) + attn(64)
#define QAP 196   // qaT LDS pitch (floats): 196%32=4; 32*196*4=25088 B
#define LFP 132   // gemm_val transpose pitch (floats): 132%32=4 spreads banks
#define WPP 33    // WXY/WA pitch (entries) per (h,p) row: 33 breaks pow2 banks

typedef float floatx4 __attribute__((ext_vector_type(4)));
typedef short bf16x8 __attribute__((ext_vector_type(8)));

__device__ __forceinline__ unsigned short f2bf_rne(float x) {
  unsigned u = __float_as_uint(x);
  return (unsigned short)((u + 0x7FFFu + ((u >> 16) & 1)) >> 16);
}
__device__ __forceinline__ void split_bf(float x, unsigned short& h, unsigned short& l) {
  unsigned u = __float_as_uint(x);
  h = (unsigned short)(u >> 16);
  float r = x - __uint_as_float(u & 0xFFFF0000u);
  l = (unsigned short)(__float_as_uint(r) >> 16);
}
__device__ __forceinline__ float fast_tanh(float x) {
  float e = __expf(2.0f * x);
  return 1.0f - 2.0f / (e + 1.0f);
}
// unpack uint4 (8 bf16) -> 2x floatx4, fused multiply-accumulate by scalar wc
__device__ __forceinline__ void bf8_fma(floatx4& oa, floatx4& ob, const uint4 r, const float wc) {
  floatx4 va = {__uint_as_float(r.x << 16), __uint_as_float(r.x & 0xFFFF0000u),
                __uint_as_float(r.y << 16), __uint_as_float(r.y & 0xFFFF0000u)};
  floatx4 vb = {__uint_as_float(r.z << 16), __uint_as_float(r.z & 0xFFFF0000u),
                __uint_as_float(r.w << 16), __uint_as_float(r.w & 0xFFFF0000u)};
  oa += va * wc;
  ob += vb * wc;
}

// Weight prep -> bf16 hi/lo fragment layout: element (n,k) at (k>>3)*Nn*8 + n*8 + (k&7).
__global__ __launch_bounds__(256) void prep(const float* __restrict__ Wv,
                                            const float* __restrict__ Wo,
                                            const float* __restrict__ Wa,
                                            const float* __restrict__ Ww,
                                            const float* __restrict__ bo,
                                            const float* __restrict__ ba,
                                            unsigned short* __restrict__ wf_val,
                                            unsigned short* __restrict__ wf_qa,
                                            unsigned short* __restrict__ wf_out,
                                            float* __restrict__ bias_qa) {
  const int gid = blockIdx.x * 256 + threadIdx.x;  // 14336 = 32 k4 * 448 n
  const int k4 = gid / 448;
  const int ng = gid - k4 * 448;

  const float* src;
  unsigned short* dst;
  int Nsrc, Nn, nd, n;
  if (ng < 128) {        src = Wv; dst = wf_val; Nsrc = 128; Nn = 128; n = ng;        nd = n; }
  else if (ng < 256) {   src = Wo; dst = wf_qa;  Nsrc = 128; Nn = 192; n = ng - 128;  nd = n; }
  else if (ng < 320) {   src = Wa; dst = wf_qa;  Nsrc = 64;  Nn = 192; n = ng - 256;  nd = n + 128; }
  else {                 src = Ww; dst = wf_out; Nsrc = 128; Nn = 128; n = ng - 320;  nd = n; }

  ushort4 hi, lo;
  split_bf(src[(k4 * 4 + 0) * Nsrc + n], hi.x, lo.x);
  split_bf(src[(k4 * 4 + 1) * Nsrc + n], hi.y, lo.y);
  split_bf(src[(k4 * 4 + 2) * Nsrc + n], hi.z, lo.z);
  split_bf(src[(k4 * 4 + 3) * Nsrc + n], hi.w, lo.w);
  const int off = (k4 >> 1) * Nn * 8 + nd * 8 + (k4 & 1) * 4;
  *(ushort4*)(dst + off) = hi;
  *(ushort4*)(dst + Nn * 128 + off) = lo;

  if (gid < 128) bias_qa[gid] = bo[gid];
  else if (gid < 192) bias_qa[gid] = ba[gid - 128];
}

// K1: value projection. Tile 64 m x 128 n, 256 thr (4 waves, wave = 32m x 64n).
// 3-term bf16 split. Epilogue: LDS transpose -> COALESCED uint4 bf16 stores.
__global__ __launch_bounds__(256, 4) void gemm_val(const float* __restrict__ nbr,
                                                   const unsigned short* __restrict__ WF,
                                                   const float* __restrict__ bias,
                                                   unsigned short* __restrict__ value) {
  __shared__ __align__(16) char smem[33792];   // staging 32768; transpose 64*132*4=33792
  unsigned short* AB = (unsigned short*)smem;  // hi [64][128]; lo at +8192 us
  const int t = threadIdx.x;
  const int ml0 = blockIdx.x * 64;
  const int b = blockIdx.y;

  {
    const float* src = nbr + (size_t)b * CM * LTOT + ml0;
    const int x = t & 63, kq = t >> 6;
#pragma unroll
    for (int i = 0; i < 8; i++) {
      const int kb = kq * 4 + i * 16;
      ushort4 hi, lo;
      split_bf(src[(size_t)(kb + 0) * LTOT + x], hi.x, lo.x);
      split_bf(src[(size_t)(kb + 1) * LTOT + x], hi.y, lo.y);
      split_bf(src[(size_t)(kb + 2) * LTOT + x], hi.z, lo.z);
      split_bf(src[(size_t)(kb + 3) * LTOT + x], hi.w, lo.w);
      const int off = x * 128 + (((kb >> 3) ^ (x & 15)) << 3) + (kb & 7);
      *(ushort4*)(AB + off) = hi;
      *(ushort4*)(AB + 8192 + off) = lo;
    }
  }
  __syncthreads();

  const int w = t >> 6, lane = t & 63;
  const int wm = (w >> 1) * 32, wn = (w & 1) * 64;
  const int nl = lane & 15, q = lane >> 4;

  floatx4 acc[2][4];
#pragma unroll
  for (int mt = 0; mt < 2; mt++)
#pragma unroll
    for (int j = 0; j < 4; j++) acc[mt][j] = {0.0f, 0.0f, 0.0f, 0.0f};

#pragma unroll
  for (int K0 = 0; K0 < 4; K0++) {
    bf16x8 ah[2], al[2];
#pragma unroll
    for (int mt = 0; mt < 2; mt++) {
      const int m = wm + mt * 16 + nl;
      const int off = m * 128 + (((K0 * 4 + q) ^ (m & 15)) << 3);
      ah[mt] = *(bf16x8*)(AB + off);
      al[mt] = *(bf16x8*)(AB + 8192 + off);
    }
#pragma unroll
    for (int j = 0; j < 4; j++) {
      const size_t o = (size_t)(K0 * 4 + q) * CM * 8 + (wn + j * 16 + nl) * 8;
      const bf16x8 wh = *(const bf16x8*)(WF + o);
      const bf16x8 wl = *(const bf16x8*)(WF + (size_t)CM * 128 + o);
#pragma unroll
      for (int mt = 0; mt < 2; mt++) {
        acc[mt][j] = __builtin_amdgcn_mfma_f32_16x16x32_bf16(al[mt], wh, acc[mt][j], 0, 0, 0);
        acc[mt][j] = __builtin_amdgcn_mfma_f32_16x16x32_bf16(ah[mt], wl, acc[mt][j], 0, 0, 0);
        acc[mt][j] = __builtin_amdgcn_mfma_f32_16x16x32_bf16(ah[mt], wh, acc[mt][j], 0, 0, 0);
      }
    }
  }

  // ---- epilogue: acc -> LDS [64 l][132] fp32 -> packed bf16 uint4 coalesced stores ----
  __syncthreads();  // AB dead
  float* LF = (float*)smem;
#pragma unroll
  for (int j = 0; j < 4; j++) {
    const int gc = wn + j * 16 + nl;
    const float bv = bias[gc];
#pragma unroll
    for (int mt = 0; mt < 2; mt++)
#pragma unroll
      for (int r = 0; r < 4; r++)
        LF[(wm + mt * 16 + q * 4 + r) * LFP + gc] = acc[mt][j][r] + bv;
  }
  __syncthreads();
  // 1024 uint4 chunks: c = h(3b) | l(6b) | half(1b); wave writes contiguous 1 KB per h
#pragma unroll
  for (int i = 0; i < 4; i++) {
    const int c = t + i * 256;
    const int h = c >> 7, rem = c & 127, l = rem >> 1, half = rem & 1;
    const float* sp = LF + l * LFP + h * 16 + half * 8;
    uint4 st;
    st.x = ((unsigned)f2bf_rne(sp[1]) << 16) | f2bf_rne(sp[0]);
    st.y = ((unsigned)f2bf_rne(sp[3]) << 16) | f2bf_rne(sp[2]);
    st.z = ((unsigned)f2bf_rne(sp[5]) << 16) | f2bf_rne(sp[4]);
    st.w = ((unsigned)f2bf_rne(sp[7]) << 16) | f2bf_rne(sp[6]);
    *(uint4*)(value + ((size_t)(b * NHEAD + h) * LTOT + ml0 + l) * DHD + half * 8) = st;
  }
}

// K2 (R7): same algorithm as R6 (h-sequenced gather, WXY/WA handoff) but 512 THREADS
// (8 waves). R6 confirmed L1-window theory (58->42.9us) yet occupancy 21%, all pipes
// idle -> phase-chain latency-bound with only 4 waves/block. 8 waves halve per-thread
// work per phase: qa GEMM wave=16mx48n acc[3]; gather wave w owns HEAD w exactly
// (hi2 loop gone, wave-uniform head preserved); out GEMM wave=16mx32n acc[2].
// LDS unchanged 33792 -> 4 blocks/CU x 8 waves = 32 waves/CU cap. Params phase runs
// on t<256 with barriers hoisted outside the conditional (all waves reach them).
// Spill guard: hbm_bytes must stay ~3.0e7.
__global__ __launch_bounds__(512, 2) void samp(const float* __restrict__ ext,
                                               const unsigned short* __restrict__ value,
                                               const unsigned short* __restrict__ wf_qa,
                                               const unsigned short* __restrict__ wf_out,
                                               const float* __restrict__ bias_qa,
                                               const float* __restrict__ b_out,
                                               float* __restrict__ out) {
  __shared__ __align__(16) char smem[33792];
  unsigned short* AB = (unsigned short*)smem;   // [0,16384): staging hi/lo
  float* qaT = (float*)smem;                    // [0,25088)
  float2* WXY = (float2*)smem;                  // [8h*8p][WPP] float2 = 16896 B at 0
  float* WA = (float*)(smem + 16896);           // [8h*8p][WPP] float  =  8448 B
  unsigned short* FR = (unsigned short*)(smem + 25344);  // [32][128] bf16 = 8192 B

  const int t = threadIdx.x;
  const int b = blockIdx.x & 7;                // XCD affinity
  const int ml0 = (blockIdx.x >> 3) * 32;
  const int w = t >> 6, lane = t & 63;
  const int nl = lane & 15, q = lane >> 4;

  // ---- stage ext 32-l tile (fp32 -> bf16 hi/lo, swizzled); 512 thr -> 2 iters ----
  {
    const float* src = ext + (size_t)b * CM * LTOT + ml0;
    const int x = t & 31, kq = t >> 5;  // kq 0..15
#pragma unroll
    for (int i = 0; i < 2; i++) {
      const int kb = i * 64 + kq * 4;
      ushort4 hi, lo;
      split_bf(src[(size_t)(kb + 0) * LTOT + x], hi.x, lo.x);
      split_bf(src[(size_t)(kb + 1) * LTOT + x], hi.y, lo.y);
      split_bf(src[(size_t)(kb + 2) * LTOT + x], hi.z, lo.z);
      split_bf(src[(size_t)(kb + 3) * LTOT + x], hi.w, lo.w);
      const int off = x * 128 + (((kb >> 3) ^ (x & 15)) << 3) + (kb & 7);
      *(ushort4*)(AB + off) = hi;
      *(ushort4*)(AB + 4096 + off) = lo;
    }
  }
  __syncthreads();

  // ---- qa GEMM: 32m x 192n, 8 waves, wave = 16m x 48n; result -> qaT (LDS) ----
  {
    const int wm = (w & 1) * 16;
    const int wn = (w >> 1) * 48;
    floatx4 acc[3];
#pragma unroll
    for (int j = 0; j < 3; j++) acc[j] = {0.0f, 0.0f, 0.0f, 0.0f};
#pragma unroll
    for (int K0 = 0; K0 < 4; K0++) {
      const int m = wm + nl;
      const int off = m * 128 + (((K0 * 4 + q) ^ (m & 15)) << 3);
      const bf16x8 ah = *(bf16x8*)(AB + off);
      const bf16x8 al = *(bf16x8*)(AB + 4096 + off);
#pragma unroll
      for (int j = 0; j < 3; j++) {
        const size_t o = (size_t)(K0 * 4 + q) * NQA * 8 + (wn + j * 16 + nl) * 8;
        const bf16x8 wh = *(const bf16x8*)(wf_qa + o);
        const bf16x8 wl = *(const bf16x8*)(wf_qa + (size_t)NQA * 128 + o);
        acc[j] = __builtin_amdgcn_mfma_f32_16x16x32_bf16(al, wh, acc[j], 0, 0, 0);
        acc[j] = __builtin_amdgcn_mfma_f32_16x16x32_bf16(ah, wl, acc[j], 0, 0, 0);
        acc[j] = __builtin_amdgcn_mfma_f32_16x16x32_bf16(ah, wh, acc[j], 0, 0, 0);
      }
    }
    __syncthreads();  // all AB reads done -> qaT may overwrite
#pragma unroll
    for (int j = 0; j < 3; j++) {
      const int n = wn + j * 16 + nl;
      const float bv = bias_qa[n];
#pragma unroll
      for (int r = 0; r < 4; r++)
        qaT[(wm + q * 4 + r) * QAP + n] = acc[j][r] + bv;
    }
  }
  __syncthreads();

  // ---- sampling params: threads t<256, (ll = t>>3, h = t&7) -> WXY/WA LDS ----
  {
    float4 of[4];
    float4 lga = {0, 0, 0, 0}, lgb = {0, 0, 0, 0};
    const int ll = t >> 3, h = t & 7;
    if (t < 256) {
      const float* qrow = qaT + ll * QAP;
#pragma unroll
      for (int j = 0; j < 4; j++) of[j] = *(const float4*)(qrow + h * 16 + j * 4);
      lga = *(const float4*)(qrow + 128 + h * 8);
      lgb = *(const float4*)(qrow + 128 + h * 8 + 4);
    }
    __syncthreads();  // qaT fully read -> WXY/WA may overwrite
    if (t < 256) {
      const float lg[8] = {lga.x, lga.y, lga.z, lga.w, lgb.x, lgb.y, lgb.z, lgb.w};
      float m = lg[0];
#pragma unroll
      for (int p = 1; p < 8; p++) m = fmaxf(m, lg[p]);
      float e[8], s = 0.0f;
#pragma unroll
      for (int p = 0; p < 8; p++) { e[p] = __expf(lg[p] - m); s += e[p]; }
      const float inv = 1.0f / s;
      const int l = ml0 + ll;
      const float xf = (float)(l & (WS - 1));
      const float yf = (float)(l >> 6);
#pragma unroll
      for (int p = 0; p < 8; p++) {
        const float ox = (p & 1) ? of[p >> 1].z : of[p >> 1].x;
        const float oy = (p & 1) ? of[p >> 1].w : of[p >> 1].y;
        WXY[(h * 8 + p) * WPP + ll] = {xf + 10.0f * fast_tanh(ox), yf + 10.0f * fast_tanh(oy)};
        WA[(h * 8 + p) * WPP + ll] = e[p] * inv;
      }
    }
  }
  __syncthreads();

  // ---- gather: wave w owns head w; lane = (llq = lane>>1, half = lane&1) ----
  {
    const int llq = lane >> 1, half = lane & 1;
    const int llm = llq & 15;
    const unsigned short* vb = value + (size_t)(b * NHEAD + w) * LTOT * DHD + half * 8;
    floatx4 oa = {0.f, 0.f, 0.f, 0.f}, ob = oa;
#pragma unroll
    for (int p = 0; p < 8; p++) {
      const float2 pxy = WXY[(w * 8 + p) * WPP + llq];
      const float a = WA[(w * 8 + p) * WPP + llq];
      const float x0f = floorf(pxy.x), y0f = floorf(pxy.y);
      const float fx = pxy.x - x0f, fy = pxy.y - y0f;
      const int ix = (int)x0f, iy = (int)y0f;
      float wc[4];
      unsigned adr[4];
#pragma unroll
      for (int c = 0; c < 4; c++) {
        const int cdx = c & 1, cdy = c >> 1;
        const int jx = ix + cdx, jy = iy + cdy;
        const float wx = cdx ? fx : 1.0f - fx;
        const float wy = cdy ? fy : 1.0f - fy;
        const bool valid = ((unsigned)jx < WS) & ((unsigned)jy < HS);
        wc[c] = valid ? a * wx * wy : 0.0f;
        const int cx = min(max(jx, 0), WS - 1);
        const int cy = min(max(jy, 0), HS - 1);
        adr[c] = (unsigned)((cy << 6) + cx) * DHD;
      }
      uint4 r[4];
#pragma unroll
      for (int c = 0; c < 4; c++) r[c] = *(const uint4*)(vb + adr[c]);
#pragma unroll
      for (int c = 0; c < 4; c++) bf8_fma(oa, ob, r[c], wc[c]);
    }
    // FR: group g = w*2+half holds channels g*8..g*8+7, swizzled by llm
    const int off = llq * 128 + (((w * 2 + half) ^ llm) << 3);
    uint4 st;
    st.x = ((unsigned)f2bf_rne(oa[1]) << 16) | f2bf_rne(oa[0]);
    st.y = ((unsigned)f2bf_rne(oa[3]) << 16) | f2bf_rne(oa[2]);
    st.z = ((unsigned)f2bf_rne(ob[1]) << 16) | f2bf_rne(ob[0]);
    st.w = ((unsigned)f2bf_rne(ob[3]) << 16) | f2bf_rne(ob[2]);
    *(uint4*)(FR + off) = st;
  }
  __syncthreads();

  // ---- out GEMM: 32m x 128n, 8 waves, wave = 16m x 32n; direct float4 stores ----
  {
    const int wm = (w & 1) * 16;
    const int wn = (w >> 1) * 32;
    floatx4 acc[2];
#pragma unroll
    for (int j = 0; j < 2; j++) acc[j] = {0.0f, 0.0f, 0.0f, 0.0f};
#pragma unroll
    for (int K0 = 0; K0 < 4; K0++) {
      const int m = wm + nl;
      const int off = m * 128 + (((K0 * 4 + q) ^ (m & 15)) << 3);
      const bf16x8 ah = *(bf16x8*)(FR + off);
#pragma unroll
      for (int j = 0; j < 2; j++) {
        const int n = wn + j * 16 + nl;
        const size_t o = (size_t)(K0 * 4 + q) * CM * 8 + n * 8;
        const bf16x8 wh = *(const bf16x8*)(wf_out + o);
        const bf16x8 wl = *(const bf16x8*)(wf_out + (size_t)CM * 128 + o);
        acc[j] = __builtin_amdgcn_mfma_f32_16x16x32_bf16(ah, wl, acc[j], 0, 0, 0);
        acc[j] = __builtin_amdgcn_mfma_f32_16x16x32_bf16(ah, wh, acc[j], 0, 0, 0);
      }
    }
    // C/D: col=nl -> n, rows q*4+r -> m (contiguous in bchw) => float4 store
#pragma unroll
    for (int j = 0; j < 2; j++) {
      const int gc = wn + j * 16 + nl;
      const float bv = b_out[gc];
      float4 st = {acc[j][0] + bv, acc[j][1] + bv, acc[j][2] + bv, acc[j][3] + bv};
      *(float4*)(out + ((size_t)b * CM + gc) * LTOT + ml0 + wm + q * 4) = st;
    }
  }
}

extern "C" void kernel_launch(void* const* d_in, const int* in_sizes, int n_in,
                              void* d_out, int out_size, void* d_ws, size_t ws_size,
                              hipStream_t stream) {
  const float* nbr    = (const float*)d_in[0];
  const float* ext    = (const float*)d_in[1];
  const float* W_val  = (const float*)d_in[2];
  const float* b_val  = (const float*)d_in[3];
  const float* W_off  = (const float*)d_in[4];
  const float* b_off  = (const float*)d_in[5];
  const float* W_attn = (const float*)d_in[6];
  const float* b_attn = (const float*)d_in[7];
  const float* W_out  = (const float*)d_in[8];
  const float* b_out  = (const float*)d_in[9];
  float* out = (float*)d_out;

  unsigned short* value = (unsigned short*)d_ws;             // 8.39 MB bf16 [b][h][l][16]
  unsigned short* wf_val = value + (size_t)HB * NHEAD * LTOT * DHD;  // 64 KB
  unsigned short* wf_qa  = wf_val + 128 * 128 * 2;           // 96 KB
  unsigned short* wf_out = wf_qa + 192 * 128 * 2;            // 64 KB
  float* bias_qa = (float*)(wf_out + 128 * 128 * 2);         // 768 B

  prep<<<56, 256, 0, stream>>>(W_val, W_off, W_attn, W_out, b_off, b_attn,
                               wf_val, wf_qa, wf_out, bias_qa);
  gemm_val<<<dim3(64, HB), 256, 0, stream>>>(nbr, wf_val, b_val, value);
  samp<<<dim3(128 * HB), 512, 0, stream>>>(ext, value, wf_qa, wf_out, bias_qa, b_out, out);
}

// Round 8
// 131.764 us; speedup vs baseline: 1.2259x; 1.0024x over previous
//
#include <hip/hip_runtime.h>
#include <cstdint>

#define HB 8
#define CM 128
#define NHEAD 8
#define NPT 8
#define DHD 16
#define HS 64
#define WS 64
#define LTOT 4096
#define NQA 192   // fused off(128) + attn(64)
#define QAP 196   // qaT LDS pitch (floats): 196%32=4; 32*196*4=25088 B
#define LFP 132   // gemm_val transpose pitch (floats): 132%32=4 spreads banks
#define WPP 33    // WXY/WA pitch (entries) per (h,p) row: 33 breaks pow2 banks

typedef float floatx4 __attribute__((ext_vector_type(4)));
typedef short bf16x8 __attribute__((ext_vector_type(8)));

__device__ __forceinline__ unsigned short f2bf_rne(float x) {
  unsigned u = __float_as_uint(x);
  return (unsigned short)((u + 0x7FFFu + ((u >> 16) & 1)) >> 16);
}
__device__ __forceinline__ void split_bf(float x, unsigned short& h, unsigned short& l) {
  unsigned u = __float_as_uint(x);
  h = (unsigned short)(u >> 16);
  float r = x - __uint_as_float(u & 0xFFFF0000u);
  l = (unsigned short)(__float_as_uint(r) >> 16);
}
__device__ __forceinline__ float fast_tanh(float x) {
  float e = __expf(2.0f * x);
  return 1.0f - 2.0f / (e + 1.0f);
}
// unpack uint4 (8 bf16) -> 2x floatx4, fused multiply-accumulate by scalar wc
__device__ __forceinline__ void bf8_fma(floatx4& oa, floatx4& ob, const uint4 r, const float wc) {
  floatx4 va = {__uint_as_float(r.x << 16), __uint_as_float(r.x & 0xFFFF0000u),
                __uint_as_float(r.y << 16), __uint_as_float(r.y & 0xFFFF0000u)};
  floatx4 vb = {__uint_as_float(r.z << 16), __uint_as_float(r.z & 0xFFFF0000u),
                __uint_as_float(r.w << 16), __uint_as_float(r.w & 0xFFFF0000u)};
  oa += va * wc;
  ob += vb * wc;
}

// Weight prep -> bf16 hi/lo fragment layout: element (n,k) at (k>>3)*Nn*8 + n*8 + (k&7).
__global__ __launch_bounds__(256) void prep(const float* __restrict__ Wv,
                                            const float* __restrict__ Wo,
                                            const float* __restrict__ Wa,
                                            const float* __restrict__ Ww,
                                            const float* __restrict__ bo,
                                            const float* __restrict__ ba,
                                            unsigned short* __restrict__ wf_val,
                                            unsigned short* __restrict__ wf_qa,
                                            unsigned short* __restrict__ wf_out,
                                            float* __restrict__ bias_qa) {
  const int gid = blockIdx.x * 256 + threadIdx.x;  // 14336 = 32 k4 * 448 n
  const int k4 = gid / 448;
  const int ng = gid - k4 * 448;

  const float* src;
  unsigned short* dst;
  int Nsrc, Nn, nd, n;
  if (ng < 128) {        src = Wv; dst = wf_val; Nsrc = 128; Nn = 128; n = ng;        nd = n; }
  else if (ng < 256) {   src = Wo; dst = wf_qa;  Nsrc = 128; Nn = 192; n = ng - 128;  nd = n; }
  else if (ng < 320) {   src = Wa; dst = wf_qa;  Nsrc = 64;  Nn = 192; n = ng - 256;  nd = n + 128; }
  else {                 src = Ww; dst = wf_out; Nsrc = 128; Nn = 128; n = ng - 320;  nd = n; }

  ushort4 hi, lo;
  split_bf(src[(k4 * 4 + 0) * Nsrc + n], hi.x, lo.x);
  split_bf(src[(k4 * 4 + 1) * Nsrc + n], hi.y, lo.y);
  split_bf(src[(k4 * 4 + 2) * Nsrc + n], hi.z, lo.z);
  split_bf(src[(k4 * 4 + 3) * Nsrc + n], hi.w, lo.w);
  const int off = (k4 >> 1) * Nn * 8 + nd * 8 + (k4 & 1) * 4;
  *(ushort4*)(dst + off) = hi;
  *(ushort4*)(dst + Nn * 128 + off) = lo;

  if (gid < 128) bias_qa[gid] = bo[gid];
  else if (gid < 192) bias_qa[gid] = ba[gid - 128];
}

// K1 (R8): value projection re-tiled for TLP. R0-R7 tile was 64x128 with 512 blocks
// = 2 blocks/CU = 8 waves/CU -> latency-exposed serial chain, est ~35-40 us by
// subtraction (never in top-5; co-dominant with samp). Now 32x128 tile, 1024 blocks
// (4/CU, 16 waves/CU), wave = 16m x 64n acc[4], 48 MFMA/wave, LDS 16896 B.
// Same 3-term bf16 split, same swizzle, same coalesced uint4 epilogue.
__global__ __launch_bounds__(256, 4) void gemm_val(const float* __restrict__ nbr,
                                                   const unsigned short* __restrict__ WF,
                                                   const float* __restrict__ bias,
                                                   unsigned short* __restrict__ value) {
  __shared__ __align__(16) char smem[16896];   // staging 16384; transpose 32*132*4=16896
  unsigned short* AB = (unsigned short*)smem;  // hi [32][128]; lo at +4096 us
  const int t = threadIdx.x;
  const int ml0 = blockIdx.x * 32;
  const int b = blockIdx.y;

  {
    const float* src = nbr + (size_t)b * CM * LTOT + ml0;
    const int x = t & 31, kq = t >> 5;  // kq 0..7
#pragma unroll
    for (int i = 0; i < 4; i++) {
      const int kb = i * 32 + kq * 4;
      ushort4 hi, lo;
      split_bf(src[(size_t)(kb + 0) * LTOT + x], hi.x, lo.x);
      split_bf(src[(size_t)(kb + 1) * LTOT + x], hi.y, lo.y);
      split_bf(src[(size_t)(kb + 2) * LTOT + x], hi.z, lo.z);
      split_bf(src[(size_t)(kb + 3) * LTOT + x], hi.w, lo.w);
      const int off = x * 128 + (((kb >> 3) ^ (x & 15)) << 3) + (kb & 7);
      *(ushort4*)(AB + off) = hi;
      *(ushort4*)(AB + 4096 + off) = lo;
    }
  }
  __syncthreads();

  const int w = t >> 6, lane = t & 63;
  const int wm = (w & 1) * 16, wn = (w >> 1) * 64;
  const int nl = lane & 15, q = lane >> 4;

  floatx4 acc[4];
#pragma unroll
  for (int j = 0; j < 4; j++) acc[j] = {0.0f, 0.0f, 0.0f, 0.0f};

#pragma unroll
  for (int K0 = 0; K0 < 4; K0++) {
    const int m = wm + nl;
    const int off = m * 128 + (((K0 * 4 + q) ^ (m & 15)) << 3);
    const bf16x8 ah = *(bf16x8*)(AB + off);
    const bf16x8 al = *(bf16x8*)(AB + 4096 + off);
#pragma unroll
    for (int j = 0; j < 4; j++) {
      const size_t o = (size_t)(K0 * 4 + q) * CM * 8 + (wn + j * 16 + nl) * 8;
      const bf16x8 wh = *(const bf16x8*)(WF + o);
      const bf16x8 wl = *(const bf16x8*)(WF + (size_t)CM * 128 + o);
      acc[j] = __builtin_amdgcn_mfma_f32_16x16x32_bf16(al, wh, acc[j], 0, 0, 0);
      acc[j] = __builtin_amdgcn_mfma_f32_16x16x32_bf16(ah, wl, acc[j], 0, 0, 0);
      acc[j] = __builtin_amdgcn_mfma_f32_16x16x32_bf16(ah, wh, acc[j], 0, 0, 0);
    }
  }

  // ---- epilogue: acc -> LDS [32 l][132] fp32 -> packed bf16 uint4 coalesced stores ----
  __syncthreads();  // AB dead
  float* LF = (float*)smem;
#pragma unroll
  for (int j = 0; j < 4; j++) {
    const int gc = wn + j * 16 + nl;
    const float bv = bias[gc];
#pragma unroll
    for (int r = 0; r < 4; r++)
      LF[(wm + q * 4 + r) * LFP + gc] = acc[j][r] + bv;
  }
  __syncthreads();
  // 512 uint4 chunks: c = h(3b) | l(5b) | half(1b); wave writes contiguous 1 KB per h
#pragma unroll
  for (int i = 0; i < 2; i++) {
    const int c = t + i * 256;
    const int h = c >> 6, rem = c & 63, l = rem >> 1, half = rem & 1;
    const float* sp = LF + l * LFP + h * 16 + half * 8;
    uint4 st;
    st.x = ((unsigned)f2bf_rne(sp[1]) << 16) | f2bf_rne(sp[0]);
    st.y = ((unsigned)f2bf_rne(sp[3]) << 16) | f2bf_rne(sp[2]);
    st.z = ((unsigned)f2bf_rne(sp[5]) << 16) | f2bf_rne(sp[4]);
    st.w = ((unsigned)f2bf_rne(sp[7]) << 16) | f2bf_rne(sp[6]);
    *(uint4*)(value + ((size_t)(b * NHEAD + h) * LTOT + ml0 + l) * DHD + half * 8) = st;
  }
}

// K2 (unchanged from R7): 512 thr, h-sequenced gather, WXY/WA handoff.
// samp proven invariant (~43-45us) to occupancy 17->63%, instr count 2x, line
// layout; remaining time ~ compulsory L2 traffic + phase structure. Parked.
__global__ __launch_bounds__(512, 2) void samp(const float* __restrict__ ext,
                                               const unsigned short* __restrict__ value,
                                               const unsigned short* __restrict__ wf_qa,
                                               const unsigned short* __restrict__ wf_out,
                                               const float* __restrict__ bias_qa,
                                               const float* __restrict__ b_out,
                                               float* __restrict__ out) {
  __shared__ __align__(16) char smem[33792];
  unsigned short* AB = (unsigned short*)smem;   // [0,16384): staging hi/lo
  float* qaT = (float*)smem;                    // [0,25088)
  float2* WXY = (float2*)smem;                  // [8h*8p][WPP] float2 = 16896 B at 0
  float* WA = (float*)(smem + 16896);           // [8h*8p][WPP] float  =  8448 B
  unsigned short* FR = (unsigned short*)(smem + 25344);  // [32][128] bf16 = 8192 B

  const int t = threadIdx.x;
  const int b = blockIdx.x & 7;                // XCD affinity
  const int ml0 = (blockIdx.x >> 3) * 32;
  const int w = t >> 6, lane = t & 63;
  const int nl = lane & 15, q = lane >> 4;

  // ---- stage ext 32-l tile (fp32 -> bf16 hi/lo, swizzled); 512 thr -> 2 iters ----
  {
    const float* src = ext + (size_t)b * CM * LTOT + ml0;
    const int x = t & 31, kq = t >> 5;  // kq 0..15
#pragma unroll
    for (int i = 0; i < 2; i++) {
      const int kb = i * 64 + kq * 4;
      ushort4 hi, lo;
      split_bf(src[(size_t)(kb + 0) * LTOT + x], hi.x, lo.x);
      split_bf(src[(size_t)(kb + 1) * LTOT + x], hi.y, lo.y);
      split_bf(src[(size_t)(kb + 2) * LTOT + x], hi.z, lo.z);
      split_bf(src[(size_t)(kb + 3) * LTOT + x], hi.w, lo.w);
      const int off = x * 128 + (((kb >> 3) ^ (x & 15)) << 3) + (kb & 7);
      *(ushort4*)(AB + off) = hi;
      *(ushort4*)(AB + 4096 + off) = lo;
    }
  }
  __syncthreads();

  // ---- qa GEMM: 32m x 192n, 8 waves, wave = 16m x 48n; result -> qaT (LDS) ----
  {
    const int wm = (w & 1) * 16;
    const int wn = (w >> 1) * 48;
    floatx4 acc[3];
#pragma unroll
    for (int j = 0; j < 3; j++) acc[j] = {0.0f, 0.0f, 0.0f, 0.0f};
#pragma unroll
    for (int K0 = 0; K0 < 4; K0++) {
      const int m = wm + nl;
      const int off = m * 128 + (((K0 * 4 + q) ^ (m & 15)) << 3);
      const bf16x8 ah = *(bf16x8*)(AB + off);
      const bf16x8 al = *(bf16x8*)(AB + 4096 + off);
#pragma unroll
      for (int j = 0; j < 3; j++) {
        const size_t o = (size_t)(K0 * 4 + q) * NQA * 8 + (wn + j * 16 + nl) * 8;
        const bf16x8 wh = *(const bf16x8*)(wf_qa + o);
        const bf16x8 wl = *(const bf16x8*)(wf_qa + (size_t)NQA * 128 + o);
        acc[j] = __builtin_amdgcn_mfma_f32_16x16x32_bf16(al, wh, acc[j], 0, 0, 0);
        acc[j] = __builtin_amdgcn_mfma_f32_16x16x32_bf16(ah, wl, acc[j], 0, 0, 0);
        acc[j] = __builtin_amdgcn_mfma_f32_16x16x32_bf16(ah, wh, acc[j], 0, 0, 0);
      }
    }
    __syncthreads();  // all AB reads done -> qaT may overwrite
#pragma unroll
    for (int j = 0; j < 3; j++) {
      const int n = wn + j * 16 + nl;
      const float bv = bias_qa[n];
#pragma unroll
      for (int r = 0; r < 4; r++)
        qaT[(wm + q * 4 + r) * QAP + n] = acc[j][r] + bv;
    }
  }
  __syncthreads();

  // ---- sampling params: threads t<256, (ll = t>>3, h = t&7) -> WXY/WA LDS ----
  {
    float4 of[4];
    float4 lga = {0, 0, 0, 0}, lgb = {0, 0, 0, 0};
    const int ll = t >> 3, h = t & 7;
    if (t < 256) {
      const float* qrow = qaT + ll * QAP;
#pragma unroll
      for (int j = 0; j < 4; j++) of[j] = *(const float4*)(qrow + h * 16 + j * 4);
      lga = *(const float4*)(qrow + 128 + h * 8);
      lgb = *(const float4*)(qrow + 128 + h * 8 + 4);
    }
    __syncthreads();  // qaT fully read -> WXY/WA may overwrite
    if (t < 256) {
      const float lg[8] = {lga.x, lga.y, lga.z, lga.w, lgb.x, lgb.y, lgb.z, lgb.w};
      float m = lg[0];
#pragma unroll
      for (int p = 1; p < 8; p++) m = fmaxf(m, lg[p]);
      float e[8], s = 0.0f;
#pragma unroll
      for (int p = 0; p < 8; p++) { e[p] = __expf(lg[p] - m); s += e[p]; }
      const float inv = 1.0f / s;
      const int l = ml0 + ll;
      const float xf = (float)(l & (WS - 1));
      const float yf = (float)(l >> 6);
#pragma unroll
      for (int p = 0; p < 8; p++) {
        const float ox = (p & 1) ? of[p >> 1].z : of[p >> 1].x;
        const float oy = (p & 1) ? of[p >> 1].w : of[p >> 1].y;
        WXY[(h * 8 + p) * WPP + ll] = {xf + 10.0f * fast_tanh(ox), yf + 10.0f * fast_tanh(oy)};
        WA[(h * 8 + p) * WPP + ll] = e[p] * inv;
      }
    }
  }
  __syncthreads();

  // ---- gather: wave w owns head w; lane = (llq = lane>>1, half = lane&1) ----
  {
    const int llq = lane >> 1, half = lane & 1;
    const int llm = llq & 15;
    const unsigned short* vb = value + (size_t)(b * NHEAD + w) * LTOT * DHD + half * 8;
    floatx4 oa = {0.f, 0.f, 0.f, 0.f}, ob = oa;
#pragma unroll
    for (int p = 0; p < 8; p++) {
      const float2 pxy = WXY[(w * 8 + p) * WPP + llq];
      const float a = WA[(w * 8 + p) * WPP + llq];
      const float x0f = floorf(pxy.x), y0f = floorf(pxy.y);
      const float fx = pxy.x - x0f, fy = pxy.y - y0f;
      const int ix = (int)x0f, iy = (int)y0f;
      float wc[4];
      unsigned adr[4];
#pragma unroll
      for (int c = 0; c < 4; c++) {
        const int cdx = c & 1, cdy = c >> 1;
        const int jx = ix + cdx, jy = iy + cdy;
        const float wx = cdx ? fx : 1.0f - fx;
        const float wy = cdy ? fy : 1.0f - fy;
        const bool valid = ((unsigned)jx < WS) & ((unsigned)jy < HS);
        wc[c] = valid ? a * wx * wy : 0.0f;
        const int cx = min(max(jx, 0), WS - 1);
        const int cy = min(max(jy, 0), HS - 1);
        adr[c] = (unsigned)((cy << 6) + cx) * DHD;
      }
      uint4 r[4];
#pragma unroll
      for (int c = 0; c < 4; c++) r[c] = *(const uint4*)(vb + adr[c]);
#pragma unroll
      for (int c = 0; c < 4; c++) bf8_fma(oa, ob, r[c], wc[c]);
    }
    // FR: group g = w*2+half holds channels g*8..g*8+7, swizzled by llm
    const int off = llq * 128 + (((w * 2 + half) ^ llm) << 3);
    uint4 st;
    st.x = ((unsigned)f2bf_rne(oa[1]) << 16) | f2bf_rne(oa[0]);
    st.y = ((unsigned)f2bf_rne(oa[3]) << 16) | f2bf_rne(oa[2]);
    st.z = ((unsigned)f2bf_rne(ob[1]) << 16) | f2bf_rne(ob[0]);
    st.w = ((unsigned)f2bf_rne(ob[3]) << 16) | f2bf_rne(ob[2]);
    *(uint4*)(FR + off) = st;
  }
  __syncthreads();

  // ---- out GEMM: 32m x 128n, 8 waves, wave = 16m x 32n; direct float4 stores ----
  {
    const int wm = (w & 1) * 16;
    const int wn = (w >> 1) * 32;
    floatx4 acc[2];
#pragma unroll
    for (int j = 0; j < 2; j++) acc[j] = {0.0f, 0.0f, 0.0f, 0.0f};
#pragma unroll
    for (int K0 = 0; K0 < 4; K0++) {
      const int m = wm + nl;
      const int off = m * 128 + (((K0 * 4 + q) ^ (m & 15)) << 3);
      const bf16x8 ah = *(bf16x8*)(FR + off);
#pragma unroll
      for (int j = 0; j < 2; j++) {
        const int n = wn + j * 16 + nl;
        const size_t o = (size_t)(K0 * 4 + q) * CM * 8 + n * 8;
        const bf16x8 wh = *(const bf16x8*)(wf_out + o);
        const bf16x8 wl = *(const bf16x8*)(wf_out + (size_t)CM * 128 + o);
        acc[j] = __builtin_amdgcn_mfma_f32_16x16x32_bf16(ah, wl, acc[j], 0, 0, 0);
        acc[j] = __builtin_amdgcn_mfma_f32_16x16x32_bf16(ah, wh, acc[j], 0, 0, 0);
      }
    }
    // C/D: col=nl -> n, rows q*4+r -> m (contiguous in bchw) => float4 store
#pragma unroll
    for (int j = 0; j < 2; j++) {
      const int gc = wn + j * 16 + nl;
      const float bv = b_out[gc];
      float4 st = {acc[j][0] + bv, acc[j][1] + bv, acc[j][2] + bv, acc[j][3] + bv};
      *(float4*)(out + ((size_t)b * CM + gc) * LTOT + ml0 + wm + q * 4) = st;
    }
  }
}

extern "C" void kernel_launch(void* const* d_in, const int* in_sizes, int n_in,
                              void* d_out, int out_size, void* d_ws, size_t ws_size,
                              hipStream_t stream) {
  const float* nbr    = (const float*)d_in[0];
  const float* ext    = (const float*)d_in[1];
  const float* W_val  = (const float*)d_in[2];
  const float* b_val  = (const float*)d_in[3];
  const float* W_off  = (const float*)d_in[4];
  const float* b_off  = (const float*)d_in[5];
  const float* W_attn = (const float*)d_in[6];
  const float* b_attn = (const float*)d_in[7];
  const float* W_out  = (const float*)d_in[8];
  const float* b_out  = (const float*)d_in[9];
  float* out = (float*)d_out;

  unsigned short* value = (unsigned short*)d_ws;             // 8.39 MB bf16 [b][h][l][16]
  unsigned short* wf_val = value + (size_t)HB * NHEAD * LTOT * DHD;  // 64 KB
  unsigned short* wf_qa  = wf_val + 128 * 128 * 2;           // 96 KB
  unsigned short* wf_out = wf_qa + 192 * 128 * 2;            // 64 KB
  float* bias_qa = (float*)(wf_out + 128 * 128 * 2);         // 768 B

  prep<<<56, 256, 0, stream>>>(W_val, W_off, W_attn, W_out, b_off, b_attn,
                               wf_val, wf_qa, wf_out, bias_qa);
  gemm_val<<<dim3(128, HB), 256, 0, stream>>>(nbr, wf_val, b_val, value);
  samp<<<dim3(128 * HB), 512, 0, stream>>>(ext, value, wf_qa, wf_out, bias_qa, b_out, out);
}